// Round 5
// baseline (3302.868 us; speedup 1.0000x reference)
//
#include <hip/hip_runtime.h>
#include <hip/hip_bf16.h>

#define SEQ 512
#define BATCH 64
#define IN 256
#define HID 512
#define NG 1536  // 3*HID

typedef short short8 __attribute__((ext_vector_type(8)));
typedef float f32x4 __attribute__((ext_vector_type(4)));

__device__ __forceinline__ unsigned short f2bf(float f) {
    union { float f; unsigned u; } v; v.f = f;
    return (unsigned short)((v.u + 0x7fffu + ((v.u >> 16) & 1u)) >> 16);
}
__device__ __forceinline__ float bf2f(unsigned short h) {
    union { unsigned u; float f; } v; v.u = ((unsigned)h) << 16; return v.f;
}

// Build gate-major bf16 weight blocks + folded bias constants.
__global__ void prep_weights(const float* __restrict__ Wr, const float* __restrict__ br,
                             const float* __restrict__ Wu, const float* __restrict__ bu,
                             const float* __restrict__ Wni, const float* __restrict__ bni,
                             const float* __restrict__ Wnh, const float* __restrict__ bnh,
                             unsigned short* __restrict__ WxT, unsigned short* __restrict__ WhT,
                             float* __restrict__ biases)
{
    int n = blockIdx.x * blockDim.x + threadIdx.x;
    if (n >= NG) return;
    int g = n >> 9, j = n & 511;
    const float* xsrc; const float* hsrc; float bias;
    if (g == 0)      { xsrc = Wr + (size_t)j*770; hsrc = Wr + (size_t)j*770 + 257;
                       bias = Wr[(size_t)j*770+256] + Wr[(size_t)j*770+769] + br[j]; }
    else if (g == 1) { xsrc = Wu + (size_t)j*770; hsrc = Wu + (size_t)j*770 + 257;
                       bias = Wu[(size_t)j*770+256] + Wu[(size_t)j*770+769] + bu[j]; }
    else             { xsrc = Wni + (size_t)j*257; hsrc = Wnh + (size_t)j*513;
                       bias = Wni[(size_t)j*257+256] + bni[j]; }
    for (int i = 0; i < IN; ++i)  WxT[(size_t)n*IN + i]  = f2bf(xsrc[i]);
    for (int k = 0; k < HID; ++k) WhT[(size_t)n*HID + k] = f2bf(hsrc[k]);
    biases[n] = bias;
    if (g == 2) biases[NG + j] = Wnh[(size_t)j*513 + 512] + bnh[j];
}

__global__ void cvt_x(const float* __restrict__ x, unsigned short* __restrict__ xb, int n)
{
    int i = (blockIdx.x * blockDim.x + threadIdx.x) * 4;
    if (i >= n) return;
    float4 v = *reinterpret_cast<const float4*>(x + i);
    ushort4 o;
    o.x = f2bf(v.x); o.y = f2bf(v.y); o.z = f2bf(v.z); o.w = f2bf(v.w);
    *reinterpret_cast<ushort4*>(xb + i) = o;
}

// Gx[m][n] = sum_i xb[m][i]*WxT[n][i] + biases[n],  m = t*64+b, stored bf16.
__global__ __launch_bounds__(256) void gemm_x(const unsigned short* __restrict__ xb,
                                              const unsigned short* __restrict__ WxT,
                                              const float* __restrict__ biases,
                                              unsigned short* __restrict__ Gx)
{
    const int lane = threadIdx.x & 63;
    const int wave = threadIdx.x >> 6;
    const int m0 = blockIdx.x * 64;
    const int n0 = blockIdx.y * 256 + wave * 64;
    const int laneM = lane & 15, laneK8 = (lane >> 4) * 8;
    f32x4 acc[4][4] = {};
#pragma unroll
    for (int k0 = 0; k0 < IN; k0 += 32) {
        short8 A[4], Bf[4];
#pragma unroll
        for (int mi = 0; mi < 4; ++mi)
            A[mi] = *reinterpret_cast<const short8*>(xb + (size_t)(m0 + mi*16 + laneM)*IN + k0 + laneK8);
#pragma unroll
        for (int ni = 0; ni < 4; ++ni)
            Bf[ni] = *reinterpret_cast<const short8*>(WxT + (size_t)(n0 + ni*16 + laneM)*IN + k0 + laneK8);
#pragma unroll
        for (int mi = 0; mi < 4; ++mi)
#pragma unroll
            for (int ni = 0; ni < 4; ++ni)
                acc[mi][ni] = __builtin_amdgcn_mfma_f32_16x16x32_bf16(A[mi], Bf[ni], acc[mi][ni], 0, 0, 0);
    }
    const int crow = (lane >> 4) * 4, ccol = lane & 15;
#pragma unroll
    for (int mi = 0; mi < 4; ++mi)
#pragma unroll
        for (int ni = 0; ni < 4; ++ni) {
            int nn = n0 + ni*16 + ccol;
            float bias = biases[nn];
#pragma unroll
            for (int v = 0; v < 4; ++v) {
                int mm = m0 + mi*16 + crow + v;
                Gx[(size_t)mm * NG + nn] = f2bf(acc[mi][ni][v] + bias);
            }
        }
}

// Persistent recurrent kernel. 128 blocks x 256 threads (cooperative launch).
// 8 groups x 8 batch rows; group membership NEGOTIATED at runtime from the
// actual XCD (HW_REG_XCC_ID) so every group's 16 blocks share one XCD L2.
// Sync: producers drain data stores (vmcnt(0) + block barrier, same-L2
// ordering) then store a per-block step-numbered flag. Consumers spin on ONE
// 16-dword flag load (local L2), then read data in a single local sweep.
// Fallback (any placement anomaly): every-8th-sweep global flag probe +
// tagged global-merge of data words — self-validating, deadlock-free.
__global__ __launch_bounds__(256, 1) void gru_seq(const unsigned short* __restrict__ Gx,
                                                  const unsigned short* __restrict__ WhT,
                                                  const float* __restrict__ biases,
                                                  unsigned* __restrict__ htagL,
                                                  unsigned* __restrict__ htagG,
                                                  unsigned* __restrict__ flagL,
                                                  unsigned* __restrict__ flagG,
                                                  unsigned* __restrict__ nego,
                                                  float* __restrict__ out)
{
    __shared__ int s_role;
    // ---- XCD discovery + role negotiation ----
    unsigned xv;
    asm volatile("s_getreg_b32 %0, hwreg(HW_REG_XCC_ID)" : "=s"(xv));
    const int myxcd = (int)(xv & 7u);
    if (threadIdx.x == 0) {
        unsigned slot = atomicAdd(&nego[myxcd], 1u);
        s_role = (slot < 16u) ? (myxcd * 16 + (int)slot) : -1;
    }
    __syncthreads();
    int role = s_role;
    // one-shot grid barrier (all registrations visible)
    if (threadIdx.x == 0) {
        unsigned old = __hip_atomic_fetch_add(&nego[12], 1u, __ATOMIC_ACQ_REL, __HIP_MEMORY_SCOPE_AGENT);
        if (old == gridDim.x - 1)
            __hip_atomic_store(&nego[13], 1u, __ATOMIC_RELEASE, __HIP_MEMORY_SCOPE_AGENT);
        else
            while (!__hip_atomic_load(&nego[13], __ATOMIC_ACQUIRE, __HIP_MEMORY_SCOPE_AGENT)) {}
    }
    __syncthreads();
    if (role < 0) {
        if (threadIdx.x == 0) {
            unsigned k = atomicAdd(&nego[8], 1u);
            unsigned acc = 0; int found = 0;
            for (int x = 0; x < 8; ++x) {
                unsigned c = __hip_atomic_load(&nego[x], __ATOMIC_RELAXED, __HIP_MEMORY_SCOPE_AGENT);
                unsigned cc = c < 16u ? c : 16u;
                unsigned fr = 16u - cc;
                if (k < acc + fr) { found = x * 16 + (int)(cc + (k - acc)); break; }
                acc += fr;
            }
            s_role = found;
        }
        __syncthreads();
        role = s_role;
    }

    const int g = role >> 4, jt = role & 15;
    const int b0 = g * 8, j0 = jt * 32;
    const int lane = threadIdx.x & 63;
    const int wave = threadIdx.x >> 6;
    const int laneM = lane & 15, laneK8 = (lane >> 4) * 8;
    __shared__ float red[4][3][2][8][16];

    // Preload recurrent weight fragments once: 3 gates x 2 n-tiles x 4 k-frags.
    short8 Bf[3][2][4];
#pragma unroll
    for (int gg = 0; gg < 3; ++gg)
#pragma unroll
        for (int nt = 0; nt < 2; ++nt)
#pragma unroll
            for (int kk = 0; kk < 4; ++kk) {
                int n = gg * HID + j0 + nt * 16 + laneM;
                int k = wave * 128 + kk * 32 + laneK8;
                Bf[gg][nt][kk] = *reinterpret_cast<const short8*>(WhT + (size_t)n * HID + k);
            }

    const int row = threadIdx.x >> 5, col = threadIdx.x & 31;   // 8 x 32 epilogue map
    const int b = b0 + row, jj = j0 + col;
    const float cnh = biases[NG + jj];
    float h_old = 0.f;
    const size_t gx0 = (size_t)b * NG + jj;
    unsigned short pr = Gx[gx0], pu = Gx[gx0 + HID], pn = Gx[gx0 + 2*HID];

    // Per-thread data base: row b0+(laneM&7) (rows 8-15 mirror 0-7), wave k-slice.
    const size_t kbase = (size_t)(b0 + (laneM & 7)) * HID + wave * 128 + laneK8;
    const int flane = lane & 15;

    for (int t = 0; t < SEQ; ++t) {
        // Prefetch next step's x-projections (independent, overlaps the wait).
        unsigned short nr = 0, nu = 0, nn2 = 0;
        if (t + 1 < SEQ) {
            size_t gi = gx0 + (size_t)(t + 1) * BATCH * NG;
            nr = Gx[gi]; nu = Gx[gi + HID]; nn2 = Gx[gi + 2*HID];
        }

        // ---- Flag wait: 16 producer flags must equal t ----
        {
            const size_t foff = (size_t)(t & 1) * 256 + (size_t)g * 32 + flane;
            const volatile unsigned* lf = (const volatile unsigned*)flagL + foff;
            const unsigned* gf = flagG + foff;
            const unsigned needF = (unsigned)t;
            int sweep = 0;
            for (;;) {
                unsigned fv = ((sweep & 7) == 7)
                    ? __hip_atomic_load(gf, __ATOMIC_RELAXED, __HIP_MEMORY_SCOPE_AGENT)
                    : *lf;
                if (__all(fv == needF)) break;
                ++sweep;
            }
        }

        // ---- Data read: one local sweep; tagged global-merge fallback ----
        const unsigned need = (unsigned)t << 16;
        const size_t pbase = (size_t)(t & 1) * BATCH * HID + kbase;
        const volatile unsigned* lp = (const volatile unsigned*)htagL + pbase;
        const unsigned* gp = htagG + pbase;
        unsigned cur[32];
#pragma unroll
        for (int f = 0; f < 4; ++f)
#pragma unroll
            for (int w = 0; w < 8; ++w)
                cur[f*8+w] = lp[f*32 + w];
        unsigned bad = 0;
#pragma unroll
        for (int w = 0; w < 32; ++w) bad |= (cur[w] ^ need) & 0xffff0000u;
        while (!__all(bad == 0)) {
            unsigned nw[32];
#pragma unroll
            for (int f = 0; f < 4; ++f)
#pragma unroll
                for (int w = 0; w < 8; ++w)
                    nw[f*8+w] = __hip_atomic_load(gp + f*32 + w, __ATOMIC_RELAXED, __HIP_MEMORY_SCOPE_AGENT);
            bad = 0;
#pragma unroll
            for (int w = 0; w < 32; ++w) {
                cur[w] = ((cur[w] ^ need) & 0xffff0000u) ? nw[w] : cur[w];
                bad |= (cur[w] ^ need) & 0xffff0000u;
            }
        }

        // Pack bf16 payloads into MFMA A fragments.
        short8 A[4];
#pragma unroll
        for (int kk = 0; kk < 4; ++kk) {
            union { unsigned p[4]; short8 s; } pk;
#pragma unroll
            for (int i = 0; i < 4; ++i)
                pk.p[i] = (cur[kk*8 + 2*i] & 0xffffu) | (cur[kk*8 + 2*i + 1] << 16);
            A[kk] = pk.s;
        }

        f32x4 acc[3][2] = {};
#pragma unroll
        for (int kk = 0; kk < 4; ++kk)
#pragma unroll
            for (int gg = 0; gg < 3; ++gg)
#pragma unroll
                for (int nt = 0; nt < 2; ++nt)
                    acc[gg][nt] = __builtin_amdgcn_mfma_f32_16x16x32_bf16(A[kk], Bf[gg][nt][kk], acc[gg][nt], 0, 0, 0);

        const int crow = (lane >> 4) * 4;
        if (crow < 8) {
#pragma unroll
            for (int v = 0; v < 4; ++v)
#pragma unroll
                for (int gg = 0; gg < 3; ++gg)
#pragma unroll
                    for (int nt = 0; nt < 2; ++nt)
                        red[wave][gg][nt][crow + v][laneM] = acc[gg][nt][v];
        }
        __syncthreads();
        const int nt = col >> 4, c16 = col & 15;
        float rp = red[0][0][nt][row][c16] + red[1][0][nt][row][c16] + red[2][0][nt][row][c16] + red[3][0][nt][row][c16];
        float up = red[0][1][nt][row][c16] + red[1][1][nt][row][c16] + red[2][1][nt][row][c16] + red[3][1][nt][row][c16];
        float np = red[0][2][nt][row][c16] + red[1][2][nt][row][c16] + red[2][2][nt][row][c16] + red[3][2][nt][row][c16];
        float r = 1.f / (1.f + __expf(-(bf2f(pr) + rp)));
        float z = 1.f / (1.f + __expf(-(bf2f(pu) + up)));
        float e = __expf(2.f * (bf2f(pn) + r * (np + cnh)));
        float n = 1.f - 2.f / (e + 1.f);
        float hnew = (1.f - z) * n + z * h_old;
        h_old = hnew;

        // Publish tagged h_{t+1}: volatile -> local L2 mirror, atomic -> memory-side.
        unsigned word = ((unsigned)(t + 1) << 16) | (unsigned)f2bf(hnew);
        size_t pidx = (size_t)((t + 1) & 1) * BATCH * HID + (size_t)b * HID + jj;
        ((volatile unsigned*)htagL)[pidx] = word;
        __hip_atomic_store(htagG + pidx, word, __ATOMIC_RELAXED, __HIP_MEMORY_SCOPE_AGENT);

        out[(size_t)t * BATCH * HID + (size_t)b * HID + jj] = hnew;
        if (t == SEQ - 1) out[(size_t)SEQ * BATCH * HID + (size_t)b * HID + jj] = hnew;
        pr = nr; pu = nu; pn = nn2;

        // Drain data stores, block-wide, then raise this block's flag.
        asm volatile("s_waitcnt vmcnt(0)" ::: "memory");
        __syncthreads();   // also protects red[] (WAR) for next iteration
        if (threadIdx.x == 0) {
            size_t fo = (size_t)((t + 1) & 1) * 256 + (size_t)g * 32 + jt;
            ((volatile unsigned*)flagL)[fo] = (unsigned)(t + 1);
            __hip_atomic_store(flagG + fo, (unsigned)(t + 1), __ATOMIC_RELAXED, __HIP_MEMORY_SCOPE_AGENT);
        }
    }
}

extern "C" void kernel_launch(void* const* d_in, const int* in_sizes, int n_in,
                              void* d_out, int out_size, void* d_ws, size_t ws_size,
                              hipStream_t stream)
{
    const float* x   = (const float*)d_in[0];
    const float* Wr  = (const float*)d_in[1];
    const float* br  = (const float*)d_in[2];
    const float* Wu  = (const float*)d_in[3];
    const float* bu  = (const float*)d_in[4];
    const float* Wni = (const float*)d_in[5];
    const float* bni = (const float*)d_in[6];
    const float* Wnh = (const float*)d_in[7];
    const float* bnh = (const float*)d_in[8];
    float* out = (float*)d_out;

    char* ws = (char*)d_ws;
    size_t off = 0;
    unsigned short* Gx  = (unsigned short*)(ws + off); off += (size_t)SEQ*BATCH*NG*2;   // 100.7 MB
    unsigned short* xb  = (unsigned short*)(ws + off); off += (size_t)SEQ*BATCH*IN*2;   // 16.8 MB
    unsigned short* WxT = (unsigned short*)(ws + off); off += (size_t)NG*IN*2;
    unsigned short* WhT = (unsigned short*)(ws + off); off += (size_t)NG*HID*2;
    float* biases       = (float*)(ws + off);          off += (size_t)(NG+HID)*4;
    unsigned* htagL     = (unsigned*)(ws + off);       off += (size_t)2*BATCH*HID*4;    // 256 KB local mirror
    unsigned* htagG     = (unsigned*)(ws + off);       off += (size_t)2*BATCH*HID*4;    // 256 KB memory-side
    unsigned* flagL     = (unsigned*)(ws + off);       off += (size_t)2*256*4;          // 2 KB
    unsigned* flagG     = (unsigned*)(ws + off);       off += (size_t)2*256*4;          // 2 KB
    unsigned* nego      = (unsigned*)(ws + off);       off += 64;
    size_t sync_bytes = (size_t)2*2*BATCH*HID*4 + (size_t)2*2*256*4 + 64;
    if (ws_size < off) return;

    hipLaunchKernelGGL(prep_weights, dim3(6), dim3(256), 0, stream,
                       Wr, br, Wu, bu, Wni, bni, Wnh, bnh, WxT, WhT, biases);
    hipLaunchKernelGGL(cvt_x, dim3(8192), dim3(256), 0, stream, x, xb, SEQ*BATCH*IN);
    hipLaunchKernelGGL(gemm_x, dim3(512, 6), dim3(256), 0, stream, xb, WxT, biases, Gx);
    // Zero tagged-h mirrors + flags + nego (contiguous; tag/flag 0 == valid h_0).
    hipMemsetAsync(htagL, 0, sync_bytes, stream);

    void* args[] = { &Gx, &WhT, &biases, &htagL, &htagG, &flagL, &flagG, &nego, &out };
    hipLaunchCooperativeKernel((void*)gru_seq, dim3(128), dim3(256), args, 0, stream);
}

// Round 6
// 2280.866 us; speedup vs baseline: 1.4481x; 1.4481x over previous
//
#include <hip/hip_runtime.h>
#include <hip/hip_bf16.h>

#define SEQ 512
#define BATCH 64
#define IN 256
#define HID 512
#define NG 1536  // 3*HID

typedef short short8 __attribute__((ext_vector_type(8)));
typedef float f32x4 __attribute__((ext_vector_type(4)));

__device__ __forceinline__ unsigned short f2bf(float f) {
    union { float f; unsigned u; } v; v.f = f;
    return (unsigned short)((v.u + 0x7fffu + ((v.u >> 16) & 1u)) >> 16);
}
__device__ __forceinline__ float bf2f(unsigned short h) {
    union { unsigned u; float f; } v; v.u = ((unsigned)h) << 16; return v.f;
}

// Build gate-major bf16 weight blocks + folded bias constants.
__global__ void prep_weights(const float* __restrict__ Wr, const float* __restrict__ br,
                             const float* __restrict__ Wu, const float* __restrict__ bu,
                             const float* __restrict__ Wni, const float* __restrict__ bni,
                             const float* __restrict__ Wnh, const float* __restrict__ bnh,
                             unsigned short* __restrict__ WxT, unsigned short* __restrict__ WhT,
                             float* __restrict__ biases)
{
    int n = blockIdx.x * blockDim.x + threadIdx.x;
    if (n >= NG) return;
    int g = n >> 9, j = n & 511;
    const float* xsrc; const float* hsrc; float bias;
    if (g == 0)      { xsrc = Wr + (size_t)j*770; hsrc = Wr + (size_t)j*770 + 257;
                       bias = Wr[(size_t)j*770+256] + Wr[(size_t)j*770+769] + br[j]; }
    else if (g == 1) { xsrc = Wu + (size_t)j*770; hsrc = Wu + (size_t)j*770 + 257;
                       bias = Wu[(size_t)j*770+256] + Wu[(size_t)j*770+769] + bu[j]; }
    else             { xsrc = Wni + (size_t)j*257; hsrc = Wnh + (size_t)j*513;
                       bias = Wni[(size_t)j*257+256] + bni[j]; }
    for (int i = 0; i < IN; ++i)  WxT[(size_t)n*IN + i]  = f2bf(xsrc[i]);
    for (int k = 0; k < HID; ++k) WhT[(size_t)n*HID + k] = f2bf(hsrc[k]);
    biases[n] = bias;
    if (g == 2) biases[NG + j] = Wnh[(size_t)j*513 + 512] + bnh[j];
}

__global__ void cvt_x(const float* __restrict__ x, unsigned short* __restrict__ xb, int n)
{
    int i = (blockIdx.x * blockDim.x + threadIdx.x) * 4;
    if (i >= n) return;
    float4 v = *reinterpret_cast<const float4*>(x + i);
    ushort4 o;
    o.x = f2bf(v.x); o.y = f2bf(v.y); o.z = f2bf(v.z); o.w = f2bf(v.w);
    *reinterpret_cast<ushort4*>(xb + i) = o;
}

// Gx[m][n] = sum_i xb[m][i]*WxT[n][i] + biases[n],  m = t*64+b, stored bf16.
__global__ __launch_bounds__(256) void gemm_x(const unsigned short* __restrict__ xb,
                                              const unsigned short* __restrict__ WxT,
                                              const float* __restrict__ biases,
                                              unsigned short* __restrict__ Gx)
{
    const int lane = threadIdx.x & 63;
    const int wave = threadIdx.x >> 6;
    const int m0 = blockIdx.x * 64;
    const int n0 = blockIdx.y * 256 + wave * 64;
    const int laneM = lane & 15, laneK8 = (lane >> 4) * 8;
    f32x4 acc[4][4] = {};
#pragma unroll
    for (int k0 = 0; k0 < IN; k0 += 32) {
        short8 A[4], Bf[4];
#pragma unroll
        for (int mi = 0; mi < 4; ++mi)
            A[mi] = *reinterpret_cast<const short8*>(xb + (size_t)(m0 + mi*16 + laneM)*IN + k0 + laneK8);
#pragma unroll
        for (int ni = 0; ni < 4; ++ni)
            Bf[ni] = *reinterpret_cast<const short8*>(WxT + (size_t)(n0 + ni*16 + laneM)*IN + k0 + laneK8);
#pragma unroll
        for (int mi = 0; mi < 4; ++mi)
#pragma unroll
            for (int ni = 0; ni < 4; ++ni)
                acc[mi][ni] = __builtin_amdgcn_mfma_f32_16x16x32_bf16(A[mi], Bf[ni], acc[mi][ni], 0, 0, 0);
    }
    const int crow = (lane >> 4) * 4, ccol = lane & 15;
#pragma unroll
    for (int mi = 0; mi < 4; ++mi)
#pragma unroll
        for (int ni = 0; ni < 4; ++ni) {
            int nn = n0 + ni*16 + ccol;
            float bias = biases[nn];
#pragma unroll
            for (int v = 0; v < 4; ++v) {
                int mm = m0 + mi*16 + crow + v;
                Gx[(size_t)mm * NG + nn] = f2bf(acc[mi][ni][v] + bias);
            }
        }
}

// Persistent recurrent kernel. 128 blocks x 256 threads (cooperative launch).
// 8 groups x 8 batch rows; block (g, jt) owns 32 hidden cols. Exchange per step:
//   publish: relaxed agent-scope tagged words (tag<<16 | bf16), fire-and-forget
//   hint:    one monotonic counter per group; +1 per block per step
//   consume: SPECULATIVELY issue all 32 data loads, THEN wave-0 polls the
//            counter (1 dword), barrier, validate tags, rare re-sweep merge.
// Detection latency and data latency overlap; no fences, no drains anywhere.
__global__ __launch_bounds__(256, 1) void gru_seq(const unsigned short* __restrict__ Gx,
                                                  const unsigned short* __restrict__ WhT,
                                                  const float* __restrict__ biases,
                                                  unsigned* __restrict__ htag,
                                                  unsigned* __restrict__ ctr,
                                                  float* __restrict__ out)
{
    const int blk = blockIdx.x;
    const int g = blk >> 4, jt = blk & 15;        // 8 groups x 16 j-tiles
    const int b0 = g * 8, j0 = jt * 32;
    const int lane = threadIdx.x & 63;
    const int wave = threadIdx.x >> 6;
    const int laneM = lane & 15, laneK8 = (lane >> 4) * 8;
    __shared__ float red[4][3][2][8][16];

    // Preload recurrent weight fragments once: 3 gates x 2 n-tiles x 4 k-frags.
    short8 Bf[3][2][4];
#pragma unroll
    for (int gg = 0; gg < 3; ++gg)
#pragma unroll
        for (int nt = 0; nt < 2; ++nt)
#pragma unroll
            for (int kk = 0; kk < 4; ++kk) {
                int n = gg * HID + j0 + nt * 16 + laneM;
                int k = wave * 128 + kk * 32 + laneK8;
                Bf[gg][nt][kk] = *reinterpret_cast<const short8*>(WhT + (size_t)n * HID + k);
            }

    const int row = threadIdx.x >> 5, col = threadIdx.x & 31;   // 8 x 32 epilogue map
    const int b = b0 + row, jj = j0 + col;
    const float cnh = biases[NG + jj];
    float h_old = 0.f;
    const size_t gx0 = (size_t)b * NG + jj;
    unsigned short pr = Gx[gx0], pu = Gx[gx0 + HID], pn = Gx[gx0 + 2*HID];

    // Per-thread data base: row b0+(laneM&7) (A rows 8-15 mirror 0-7), wave k-slice.
    const size_t kbase = (size_t)(b0 + (laneM & 7)) * HID + wave * 128 + laneK8;
    unsigned* myctr = ctr + (size_t)g * 16;       // 64-B separated counter lines

    for (int t = 0; t < SEQ; ++t) {
        // Prefetch next step's x-projections (independent, overlaps everything).
        unsigned short nr = 0, nu = 0, nn2 = 0;
        if (t + 1 < SEQ) {
            size_t gi = gx0 + (size_t)(t + 1) * BATCH * NG;
            nr = Gx[gi]; nu = Gx[gi + HID]; nn2 = Gx[gi + 2*HID];
        }

        // ---- Speculative data sweep: issue all 32 tagged loads NOW ----
        const unsigned need = (unsigned)t << 16;
        const unsigned* hp = htag + (size_t)(t & 1) * BATCH * HID + kbase;
        unsigned cur[32];
#pragma unroll
        for (int f = 0; f < 4; ++f)
#pragma unroll
            for (int w = 0; w < 8; ++w)
                cur[f*8+w] = __hip_atomic_load(hp + f*32 + w, __ATOMIC_RELAXED, __HIP_MEMORY_SCOPE_AGENT);

        // ---- Counter poll (wave 0 only; loads overlap the poll) ----
        if (t > 0 && wave == 0) {
            const unsigned tgt = (unsigned)(16 * t);
            while (__hip_atomic_load(myctr, __ATOMIC_RELAXED, __HIP_MEMORY_SCOPE_AGENT) < tgt) {}
        }
        __syncthreads();   // gate on poll; also drains spec loads (WAR-safe for red)

        // ---- Validate tags; rare merge re-sweep for stragglers ----
        unsigned bad = 0;
#pragma unroll
        for (int w = 0; w < 32; ++w) bad |= (cur[w] ^ need) & 0xffff0000u;
        while (!__all(bad == 0)) {
            unsigned nw[32];
#pragma unroll
            for (int f = 0; f < 4; ++f)
#pragma unroll
                for (int w = 0; w < 8; ++w)
                    nw[f*8+w] = __hip_atomic_load(hp + f*32 + w, __ATOMIC_RELAXED, __HIP_MEMORY_SCOPE_AGENT);
            bad = 0;
#pragma unroll
            for (int w = 0; w < 32; ++w) {
                cur[w] = ((cur[w] ^ need) & 0xffff0000u) ? nw[w] : cur[w];
                bad |= (cur[w] ^ need) & 0xffff0000u;
            }
        }

        // Pack bf16 payloads into MFMA A fragments.
        short8 A[4];
#pragma unroll
        for (int kk = 0; kk < 4; ++kk) {
            union { unsigned p[4]; short8 s; } pk;
#pragma unroll
            for (int i = 0; i < 4; ++i)
                pk.p[i] = (cur[kk*8 + 2*i] & 0xffffu) | (cur[kk*8 + 2*i + 1] << 16);
            A[kk] = pk.s;
        }

        f32x4 acc[3][2] = {};
#pragma unroll
        for (int kk = 0; kk < 4; ++kk)
#pragma unroll
            for (int gg = 0; gg < 3; ++gg)
#pragma unroll
                for (int nt = 0; nt < 2; ++nt)
                    acc[gg][nt] = __builtin_amdgcn_mfma_f32_16x16x32_bf16(A[kk], Bf[gg][nt][kk], acc[gg][nt], 0, 0, 0);

        const int crow = (lane >> 4) * 4;
        if (crow < 8) {
#pragma unroll
            for (int v = 0; v < 4; ++v)
#pragma unroll
                for (int gg = 0; gg < 3; ++gg)
#pragma unroll
                    for (int nt = 0; nt < 2; ++nt)
                        red[wave][gg][nt][crow + v][laneM] = acc[gg][nt][v];
        }
        __syncthreads();
        const int nt = col >> 4, c16 = col & 15;
        float rp = red[0][0][nt][row][c16] + red[1][0][nt][row][c16] + red[2][0][nt][row][c16] + red[3][0][nt][row][c16];
        float up = red[0][1][nt][row][c16] + red[1][1][nt][row][c16] + red[2][1][nt][row][c16] + red[3][1][nt][row][c16];
        float np = red[0][2][nt][row][c16] + red[1][2][nt][row][c16] + red[2][2][nt][row][c16] + red[3][2][nt][row][c16];
        float r = 1.f / (1.f + __expf(-(bf2f(pr) + rp)));
        float z = 1.f / (1.f + __expf(-(bf2f(pu) + up)));
        float e = __expf(2.f * (bf2f(pn) + r * (np + cnh)));
        float n = 1.f - 2.f / (e + 1.f);
        float hnew = (1.f - z) * n + z * h_old;
        h_old = hnew;

        // Publish tagged h_{t+1} — fire and forget.
        __hip_atomic_store(htag + (size_t)((t + 1) & 1) * BATCH * HID + (size_t)b * HID + jj,
                           ((unsigned)(t + 1) << 16) | (unsigned)f2bf(hnew),
                           __ATOMIC_RELAXED, __HIP_MEMORY_SCOPE_AGENT);

        // All threads have ISSUED their publish store (raw barrier, no drain),
        // then one thread bumps the group counter (hint only; tags gate data).
        __builtin_amdgcn_s_barrier();
        if (threadIdx.x == 0)
            __hip_atomic_fetch_add(myctr, 1u, __ATOMIC_RELAXED, __HIP_MEMORY_SCOPE_AGENT);

        // Output writes ride behind next step's poll.
        out[(size_t)t * BATCH * HID + (size_t)b * HID + jj] = hnew;
        if (t == SEQ - 1) out[(size_t)SEQ * BATCH * HID + (size_t)b * HID + jj] = hnew;
        pr = nr; pu = nu; pn = nn2;
    }
}

extern "C" void kernel_launch(void* const* d_in, const int* in_sizes, int n_in,
                              void* d_out, int out_size, void* d_ws, size_t ws_size,
                              hipStream_t stream)
{
    const float* x   = (const float*)d_in[0];
    const float* Wr  = (const float*)d_in[1];
    const float* br  = (const float*)d_in[2];
    const float* Wu  = (const float*)d_in[3];
    const float* bu  = (const float*)d_in[4];
    const float* Wni = (const float*)d_in[5];
    const float* bni = (const float*)d_in[6];
    const float* Wnh = (const float*)d_in[7];
    const float* bnh = (const float*)d_in[8];
    float* out = (float*)d_out;

    char* ws = (char*)d_ws;
    size_t off = 0;
    unsigned short* Gx  = (unsigned short*)(ws + off); off += (size_t)SEQ*BATCH*NG*2;   // 100.7 MB
    unsigned short* xb  = (unsigned short*)(ws + off); off += (size_t)SEQ*BATCH*IN*2;   // 16.8 MB
    unsigned short* WxT = (unsigned short*)(ws + off); off += (size_t)NG*IN*2;
    unsigned short* WhT = (unsigned short*)(ws + off); off += (size_t)NG*HID*2;
    float* biases       = (float*)(ws + off);          off += (size_t)(NG+HID)*4;
    unsigned* htag      = (unsigned*)(ws + off);       off += (size_t)2*BATCH*HID*4;    // 256 KB tagged h
    unsigned* ctr       = (unsigned*)(ws + off);       off += (size_t)8*16*4;           // 512 B counters
    if (ws_size < off) return;

    hipLaunchKernelGGL(prep_weights, dim3(6), dim3(256), 0, stream,
                       Wr, br, Wu, bu, Wni, bni, Wnh, bnh, WxT, WhT, biases);
    hipLaunchKernelGGL(cvt_x, dim3(8192), dim3(256), 0, stream, x, xb, SEQ*BATCH*IN);
    hipLaunchKernelGGL(gemm_x, dim3(512, 6), dim3(256), 0, stream, xb, WxT, biases, Gx);
    // Zero tagged-h + counters (contiguous; tag 0 == valid h_0 == zeros).
    hipMemsetAsync(htag, 0, (size_t)2*BATCH*HID*4 + (size_t)8*16*4, stream);

    void* args[] = { &Gx, &WhT, &biases, &htag, &ctr, &out };
    hipLaunchCooperativeKernel((void*)gru_seq, dim3(128), dim3(256), args, 0, stream);
}

// Round 7
// 2136.735 us; speedup vs baseline: 1.5458x; 1.0675x over previous
//
#include <hip/hip_runtime.h>
#include <hip/hip_bf16.h>

#define SEQ 512
#define BATCH 64
#define IN 256
#define HID 512
#define NG 1536  // 3*HID

typedef short short8 __attribute__((ext_vector_type(8)));
typedef float f32x4 __attribute__((ext_vector_type(4)));

__device__ __forceinline__ unsigned short f2bf(float f) {
    union { float f; unsigned u; } v; v.f = f;
    return (unsigned short)((v.u + 0x7fffu + ((v.u >> 16) & 1u)) >> 16);
}
__device__ __forceinline__ float bf2f(unsigned short h) {
    union { unsigned u; float f; } v; v.u = ((unsigned)h) << 16; return v.f;
}

// Build gate-major bf16 weight blocks + folded bias constants.
__global__ void prep_weights(const float* __restrict__ Wr, const float* __restrict__ br,
                             const float* __restrict__ Wu, const float* __restrict__ bu,
                             const float* __restrict__ Wni, const float* __restrict__ bni,
                             const float* __restrict__ Wnh, const float* __restrict__ bnh,
                             unsigned short* __restrict__ WxT, unsigned short* __restrict__ WhT,
                             float* __restrict__ biases)
{
    int n = blockIdx.x * blockDim.x + threadIdx.x;
    if (n >= NG) return;
    int g = n >> 9, j = n & 511;
    const float* xsrc; const float* hsrc; float bias;
    if (g == 0)      { xsrc = Wr + (size_t)j*770; hsrc = Wr + (size_t)j*770 + 257;
                       bias = Wr[(size_t)j*770+256] + Wr[(size_t)j*770+769] + br[j]; }
    else if (g == 1) { xsrc = Wu + (size_t)j*770; hsrc = Wu + (size_t)j*770 + 257;
                       bias = Wu[(size_t)j*770+256] + Wu[(size_t)j*770+769] + bu[j]; }
    else             { xsrc = Wni + (size_t)j*257; hsrc = Wnh + (size_t)j*513;
                       bias = Wni[(size_t)j*257+256] + bni[j]; }
    for (int i = 0; i < IN; ++i)  WxT[(size_t)n*IN + i]  = f2bf(xsrc[i]);
    for (int k = 0; k < HID; ++k) WhT[(size_t)n*HID + k] = f2bf(hsrc[k]);
    biases[n] = bias;
    if (g == 2) biases[NG + j] = Wnh[(size_t)j*513 + 512] + bnh[j];
}

__global__ void cvt_x(const float* __restrict__ x, unsigned short* __restrict__ xb, int n)
{
    int i = (blockIdx.x * blockDim.x + threadIdx.x) * 4;
    if (i >= n) return;
    float4 v = *reinterpret_cast<const float4*>(x + i);
    ushort4 o;
    o.x = f2bf(v.x); o.y = f2bf(v.y); o.z = f2bf(v.z); o.w = f2bf(v.w);
    *reinterpret_cast<ushort4*>(xb + i) = o;
}

// Gx[m][n] = sum_i xb[m][i]*WxT[n][i] + biases[n],  m = t*64+b, stored bf16.
__global__ __launch_bounds__(256) void gemm_x(const unsigned short* __restrict__ xb,
                                              const unsigned short* __restrict__ WxT,
                                              const float* __restrict__ biases,
                                              unsigned short* __restrict__ Gx)
{
    const int lane = threadIdx.x & 63;
    const int wave = threadIdx.x >> 6;
    const int m0 = blockIdx.x * 64;
    const int n0 = blockIdx.y * 256 + wave * 64;
    const int laneM = lane & 15, laneK8 = (lane >> 4) * 8;
    f32x4 acc[4][4] = {};
#pragma unroll
    for (int k0 = 0; k0 < IN; k0 += 32) {
        short8 A[4], Bf[4];
#pragma unroll
        for (int mi = 0; mi < 4; ++mi)
            A[mi] = *reinterpret_cast<const short8*>(xb + (size_t)(m0 + mi*16 + laneM)*IN + k0 + laneK8);
#pragma unroll
        for (int ni = 0; ni < 4; ++ni)
            Bf[ni] = *reinterpret_cast<const short8*>(WxT + (size_t)(n0 + ni*16 + laneM)*IN + k0 + laneK8);
#pragma unroll
        for (int mi = 0; mi < 4; ++mi)
#pragma unroll
            for (int ni = 0; ni < 4; ++ni)
                acc[mi][ni] = __builtin_amdgcn_mfma_f32_16x16x32_bf16(A[mi], Bf[ni], acc[mi][ni], 0, 0, 0);
    }
    const int crow = (lane >> 4) * 4, ccol = lane & 15;
#pragma unroll
    for (int mi = 0; mi < 4; ++mi)
#pragma unroll
        for (int ni = 0; ni < 4; ++ni) {
            int nn = n0 + ni*16 + ccol;
            float bias = biases[nn];
#pragma unroll
            for (int v = 0; v < 4; ++v) {
                int mm = m0 + mi*16 + crow + v;
                Gx[(size_t)mm * NG + nn] = f2bf(acc[mi][ni][v] + bias);
            }
        }
}

// Persistent recurrent kernel. 128 blocks x 256 threads (cooperative launch).
// 8 groups x 8 batch rows; block (g, jt) owns 32 hidden cols. Per step:
//   publish: relaxed agent-scope tagged words (tag<<16 | bf16)
//   drain:   s_waitcnt vmcnt(0) + block barrier  (data ACKED at coherence pt)
//   digest:  thread0 plain-stores per-block digest word = t+1 (64B-spaced,
//            no RMW, no contention)
//   consume: issue 32 spec data loads, then each wave polls the 16 digest
//            words (one 16-lane load); digest>=t implies data visible ->
//            validate tags, usually exactly one re-sweep.
__global__ __launch_bounds__(256, 1) void gru_seq(const unsigned short* __restrict__ Gx,
                                                  const unsigned short* __restrict__ WhT,
                                                  const float* __restrict__ biases,
                                                  unsigned* __restrict__ htag,
                                                  unsigned* __restrict__ dig,
                                                  float* __restrict__ out)
{
    const int blk = blockIdx.x;
    const int g = blk >> 4, jt = blk & 15;        // 8 groups x 16 j-tiles
    const int b0 = g * 8, j0 = jt * 32;
    const int lane = threadIdx.x & 63;
    const int wave = threadIdx.x >> 6;
    const int laneM = lane & 15, laneK8 = (lane >> 4) * 8;
    __shared__ float red[4][3][2][8][16];

    // Preload recurrent weight fragments once: 3 gates x 2 n-tiles x 4 k-frags.
    short8 Bf[3][2][4];
#pragma unroll
    for (int gg = 0; gg < 3; ++gg)
#pragma unroll
        for (int nt = 0; nt < 2; ++nt)
#pragma unroll
            for (int kk = 0; kk < 4; ++kk) {
                int n = gg * HID + j0 + nt * 16 + laneM;
                int k = wave * 128 + kk * 32 + laneK8;
                Bf[gg][nt][kk] = *reinterpret_cast<const short8*>(WhT + (size_t)n * HID + k);
            }

    const int row = threadIdx.x >> 5, col = threadIdx.x & 31;   // 8 x 32 epilogue map
    const int b = b0 + row, jj = j0 + col;
    const float cnh = biases[NG + jj];
    float h_old = 0.f;
    const size_t gx0 = (size_t)b * NG + jj;
    unsigned short pr = Gx[gx0], pu = Gx[gx0 + HID], pn = Gx[gx0 + 2*HID];

    // Per-thread data base: row b0+(laneM&7) (A rows 8-15 mirror 0-7), wave k-slice.
    const size_t kbase = (size_t)(b0 + (laneM & 7)) * HID + wave * 128 + laneK8;
    const unsigned* gdig = dig + (size_t)g * 256;          // 16 blocks x 16 dwords
    unsigned* mydig = dig + ((size_t)g * 16 + jt) * 16;

    for (int t = 0; t < SEQ; ++t) {
        // Prefetch next step's x-projections (independent, overlaps everything).
        unsigned short nr = 0, nu = 0, nn2 = 0;
        if (t + 1 < SEQ) {
            size_t gi = gx0 + (size_t)(t + 1) * BATCH * NG;
            nr = Gx[gi]; nu = Gx[gi + HID]; nn2 = Gx[gi + 2*HID];
        }

        // ---- Speculative data sweep: issue all 32 tagged loads NOW ----
        const unsigned need = (unsigned)t << 16;
        const unsigned* hp = htag + (size_t)(t & 1) * BATCH * HID + kbase;
        unsigned cur[32];
#pragma unroll
        for (int f = 0; f < 4; ++f)
#pragma unroll
            for (int w = 0; w < 8; ++w)
                cur[f*8+w] = __hip_atomic_load(hp + f*32 + w, __ATOMIC_RELAXED, __HIP_MEMORY_SCOPE_AGENT);

        // ---- Digest poll (every wave; 16 lanes, 16 distinct lines) ----
        if (t > 0) {
            const unsigned tgt = (unsigned)t;
            unsigned v;
            do {
                v = (lane < 16)
                    ? __hip_atomic_load(gdig + (size_t)lane * 16, __ATOMIC_RELAXED, __HIP_MEMORY_SCOPE_AGENT)
                    : tgt;
            } while (!__all(v >= tgt));
        }

        // ---- Validate tags; digest guarantees visibility -> ~1 re-sweep ----
        unsigned bad = 0;
#pragma unroll
        for (int w = 0; w < 32; ++w) bad |= (cur[w] ^ need) & 0xffff0000u;
        while (!__all(bad == 0)) {
            unsigned nw[32];
#pragma unroll
            for (int f = 0; f < 4; ++f)
#pragma unroll
                for (int w = 0; w < 8; ++w)
                    nw[f*8+w] = __hip_atomic_load(hp + f*32 + w, __ATOMIC_RELAXED, __HIP_MEMORY_SCOPE_AGENT);
            bad = 0;
#pragma unroll
            for (int w = 0; w < 32; ++w) {
                cur[w] = ((cur[w] ^ need) & 0xffff0000u) ? nw[w] : cur[w];
                bad |= (cur[w] ^ need) & 0xffff0000u;
            }
        }

        // Pack bf16 payloads into MFMA A fragments.
        short8 A[4];
#pragma unroll
        for (int kk = 0; kk < 4; ++kk) {
            union { unsigned p[4]; short8 s; } pk;
#pragma unroll
            for (int i = 0; i < 4; ++i)
                pk.p[i] = (cur[kk*8 + 2*i] & 0xffffu) | (cur[kk*8 + 2*i + 1] << 16);
            A[kk] = pk.s;
        }

        f32x4 acc[3][2] = {};
#pragma unroll
        for (int kk = 0; kk < 4; ++kk)
#pragma unroll
            for (int gg = 0; gg < 3; ++gg)
#pragma unroll
                for (int nt = 0; nt < 2; ++nt)
                    acc[gg][nt] = __builtin_amdgcn_mfma_f32_16x16x32_bf16(A[kk], Bf[gg][nt][kk], acc[gg][nt], 0, 0, 0);

        const int crow = (lane >> 4) * 4;
        if (crow < 8) {
#pragma unroll
            for (int v = 0; v < 4; ++v)
#pragma unroll
                for (int gg = 0; gg < 3; ++gg)
#pragma unroll
                    for (int nt = 0; nt < 2; ++nt)
                        red[wave][gg][nt][crow + v][laneM] = acc[gg][nt][v];
        }
        __syncthreads();
        const int nt = col >> 4, c16 = col & 15;
        float rp = red[0][0][nt][row][c16] + red[1][0][nt][row][c16] + red[2][0][nt][row][c16] + red[3][0][nt][row][c16];
        float up = red[0][1][nt][row][c16] + red[1][1][nt][row][c16] + red[2][1][nt][row][c16] + red[3][1][nt][row][c16];
        float np = red[0][2][nt][row][c16] + red[1][2][nt][row][c16] + red[2][2][nt][row][c16] + red[3][2][nt][row][c16];
        float r = 1.f / (1.f + __expf(-(bf2f(pr) + rp)));
        float z = 1.f / (1.f + __expf(-(bf2f(pu) + up)));
        float e = __expf(2.f * (bf2f(pn) + r * (np + cnh)));
        float n = 1.f - 2.f / (e + 1.f);
        float hnew = (1.f - z) * n + z * h_old;
        h_old = hnew;

        // Publish tagged h_{t+1}, then drain so the digest implies visibility.
        __hip_atomic_store(htag + (size_t)((t + 1) & 1) * BATCH * HID + (size_t)b * HID + jj,
                           ((unsigned)(t + 1) << 16) | (unsigned)f2bf(hnew),
                           __ATOMIC_RELAXED, __HIP_MEMORY_SCOPE_AGENT);
        asm volatile("s_waitcnt vmcnt(0)" ::: "memory");
        __syncthreads();   // all threads drained; also red[] WAR protection
        if (threadIdx.x == 0)
            __hip_atomic_store(mydig, (unsigned)(t + 1), __ATOMIC_RELAXED, __HIP_MEMORY_SCOPE_AGENT);

        // Output writes ride behind next step's exchange.
        out[(size_t)t * BATCH * HID + (size_t)b * HID + jj] = hnew;
        if (t == SEQ - 1) out[(size_t)SEQ * BATCH * HID + (size_t)b * HID + jj] = hnew;
        pr = nr; pu = nu; pn = nn2;
    }
}

extern "C" void kernel_launch(void* const* d_in, const int* in_sizes, int n_in,
                              void* d_out, int out_size, void* d_ws, size_t ws_size,
                              hipStream_t stream)
{
    const float* x   = (const float*)d_in[0];
    const float* Wr  = (const float*)d_in[1];
    const float* br  = (const float*)d_in[2];
    const float* Wu  = (const float*)d_in[3];
    const float* bu  = (const float*)d_in[4];
    const float* Wni = (const float*)d_in[5];
    const float* bni = (const float*)d_in[6];
    const float* Wnh = (const float*)d_in[7];
    const float* bnh = (const float*)d_in[8];
    float* out = (float*)d_out;

    char* ws = (char*)d_ws;
    size_t off = 0;
    unsigned short* Gx  = (unsigned short*)(ws + off); off += (size_t)SEQ*BATCH*NG*2;   // 100.7 MB
    unsigned short* xb  = (unsigned short*)(ws + off); off += (size_t)SEQ*BATCH*IN*2;   // 16.8 MB
    unsigned short* WxT = (unsigned short*)(ws + off); off += (size_t)NG*IN*2;
    unsigned short* WhT = (unsigned short*)(ws + off); off += (size_t)NG*HID*2;
    float* biases       = (float*)(ws + off);          off += (size_t)(NG+HID)*4;
    unsigned* htag      = (unsigned*)(ws + off);       off += (size_t)2*BATCH*HID*4;    // 256 KB tagged h
    unsigned* dig       = (unsigned*)(ws + off);       off += (size_t)8*16*16*4;        // 8 KB digests
    if (ws_size < off) return;

    hipLaunchKernelGGL(prep_weights, dim3(6), dim3(256), 0, stream,
                       Wr, br, Wu, bu, Wni, bni, Wnh, bnh, WxT, WhT, biases);
    hipLaunchKernelGGL(cvt_x, dim3(8192), dim3(256), 0, stream, x, xb, SEQ*BATCH*IN);
    hipLaunchKernelGGL(gemm_x, dim3(512, 6), dim3(256), 0, stream, xb, WxT, biases, Gx);
    // Zero tagged-h + digests (contiguous; tag/digest 0 == valid h_0 == zeros).
    hipMemsetAsync(htag, 0, (size_t)2*BATCH*HID*4 + (size_t)8*16*16*4, stream);

    void* args[] = { &Gx, &WhT, &biases, &htag, &dig, &out };
    hipLaunchCooperativeKernel((void*)gru_seq, dim3(128), dim3(256), args, 0, stream);
}